// Round 7
// baseline (338.646 us; speedup 1.0000x reference)
//
#include <hip/hip_runtime.h>

#define SLOPE 0.01f

typedef __attribute__((ext_vector_type(8))) short short8;
typedef __attribute__((ext_vector_type(4))) float f32x4;

__device__ __forceinline__ float lrelu(float v) { return v >= 0.f ? v : SLOPE * v; }

__device__ __forceinline__ unsigned short f2bf(float f) {
    union { float f; unsigned int u; } v; v.f = f;
    unsigned int r = v.u + 0x7fffu + ((v.u >> 16) & 1u);
    return (unsigned short)(r >> 16);
}
__device__ __forceinline__ float bf2f(unsigned short h) {
    union { unsigned int u; float f; } v; v.u = ((unsigned int)h) << 16;
    return v.f;
}

// MFMA A-fragment swizzle (16-oc tiles):
//   frag for (octile t, kblock kb) at lane l = W[((t*(K/32)+kb)*64+l)*8 .. +8)
__device__ __forceinline__ int swz(int oc, int k, int Kdiv32) {
    return (((oc >> 4) * Kdiv32 + (k >> 5)) * 64 + ((k >> 3) & 3) * 16 + (oc & 15)) * 8 + (k & 7);
}

// Software grid barrier: grid=256 blocks (1/CU, co-residency structurally
// guaranteed: LDS 38.4KB => >=4 blocks/CU capacity). Counter zeroed by
// hipMemsetAsync each call => deterministic across graph replays.
__device__ __forceinline__ void gbar(unsigned* __restrict__ ctr, unsigned target) {
    __threadfence();
    __syncthreads();
    if (threadIdx.x == 0) {
        __hip_atomic_fetch_add(ctr, 1u, __ATOMIC_ACQ_REL, __HIP_MEMORY_SCOPE_AGENT);
        while (__hip_atomic_load(ctr, __ATOMIC_ACQUIRE, __HIP_MEMORY_SCOPE_AGENT) < target) {
            __builtin_amdgcn_s_sleep(2);
        }
    }
    __syncthreads();
    __threadfence();
}

// ---------------------------------------------------------------------------
// Workspace (f32 slot offsets):
//   P2   bf16 [4][25][25][128]   @ 0        (160000)
//   Z2   bf16 [4][21][21][128]   @ 160000   (112896)
//   W2s  bf16 swz K=3200         @ 272896   (204800)
//   W3s  bf16 swz K=3200         @ 477696   (204800)
//   C4Bs bf16 swz K=128          @ 682496   (16384)
//   C5Bs bf16 swz K=256          @ 698880   (16384)
//   DWBs bf16 swz K=128          @ 715264   (32768)
//   Q2   bf16 [16][10][10][128]  @ 748032   (102400)
//   ctr  u32                     @ 850432   (16)
// ---------------------------------------------------------------------------

__global__ __launch_bounds__(256) void fused(
    const float* __restrict__ x,
    const float* __restrict__ c1w, const float* __restrict__ c1b,
    const float* __restrict__ c2w, const float* __restrict__ c2b,
    const float* __restrict__ c3w, const float* __restrict__ c3b,
    const float* __restrict__ c4w, const float* __restrict__ c4b,
    const float* __restrict__ c5w, const float* __restrict__ c5b,
    const float* __restrict__ dw,  const float* __restrict__ db,
    float* __restrict__ out, float* __restrict__ ws, unsigned* __restrict__ ctr) {

    __shared__ float smem[9600];

    const int tid = threadIdx.x;
    const int bid = blockIdx.x;
    const int gtid = bid * 256 + tid;

    unsigned short* P2   = (unsigned short*)(ws);
    unsigned short* Z2   = (unsigned short*)(ws + 160000);
    unsigned short* W2s  = (unsigned short*)(ws + 272896);
    unsigned short* W3s  = (unsigned short*)(ws + 477696);
    unsigned short* C4Bs = (unsigned short*)(ws + 682496);
    unsigned short* C5Bs = (unsigned short*)(ws + 698880);
    unsigned short* DWBs = (unsigned short*)(ws + 715264);
    unsigned short* Q2   = (unsigned short*)(ws + 748032);

    // ================= S0a: fused conv1+pool1 -> P2 =================
    for (int idx = tid; idx < 9600; idx += 256) smem[idx] = c1w[idx];
    __syncthreads();
    for (int q = tid; q < 1250; q += 256) {
        int t = bid * 1250 + q;           // [0, 320000)
        int ic = t & 127;
        int rest = t >> 7;
        int B = rest % 25;
        int A = (rest / 25) % 25;
        int ph = rest / 625;
        int py = ph >> 1, px = ph & 1;
        int r0 = 2 * A + py, s0 = 2 * B + px;

        float a00 = 0.f, a01 = 0.f, a10 = 0.f, a11 = 0.f;
        const float* lw = smem + ic * 75;
        for (int c = 0; c < 3; ++c) {
            const float* xc = x + c * 576;
            const float* lwc = lw + c * 25;
#pragma unroll
            for (int ky = 0; ky < 5; ++ky) {
                int iy = r0 + ky - 16;
                bool v0 = (iy >= 0) && (iy < 24);
                bool v1 = (iy + 1 >= 0) && (iy + 1 < 24);
                if (!v0 && !v1) continue;
#pragma unroll
                for (int kx = 0; kx < 5; ++kx) {
                    int ix = s0 + kx - 16;
                    float w = lwc[ky * 5 + kx];
                    bool u0 = (ix >= 0) && (ix < 24);
                    bool u1 = (ix + 1 >= 0) && (ix + 1 < 24);
                    float x00 = (v0 && u0) ? xc[iy * 24 + ix] : 0.f;
                    float x01 = (v0 && u1) ? xc[iy * 24 + ix + 1] : 0.f;
                    float x10 = (v1 && u0) ? xc[(iy + 1) * 24 + ix] : 0.f;
                    float x11 = (v1 && u1) ? xc[(iy + 1) * 24 + ix + 1] : 0.f;
                    a00 += x00 * w; a01 += x01 * w; a10 += x10 * w; a11 += x11 * w;
                }
            }
        }
        float mx = fmaxf(fmaxf(a00, a01), fmaxf(a10, a11));
        P2[t] = f2bf(lrelu(c1b[ic] + mx));
    }

    // ================= S0b: W2/W3 swizzle-transpose (1 oc-row per block) ====
    {
        int oc = bid & 127;
        const float* src = (bid < 128) ? (c2w + oc * 3200) : (c3w + oc * 3200);
        unsigned short* dst = (bid < 128) ? W2s : W3s;
        __syncthreads();
        for (int idx = tid; idx < 3200; idx += 256) smem[idx] = src[idx];
        __syncthreads();
        for (int idx = tid; idx < 3200; idx += 256) {
            int ic = idx & 127, kpos = idx >> 7;
            dst[swz(oc, kpos * 128 + ic, 100)] = f2bf(smem[ic * 25 + kpos]);
        }
    }

    // ================= S0c: swizzled bf16 casts of c4w/c5w/dw ==============
    for (int q = tid; q < 512; q += 256) {
        int e = bid * 512 + q;            // [0, 131072)
        if (e < 32768) {
            int oc = e >> 7, k = e & 127;
            C4Bs[swz(oc, k, 4)] = f2bf(c4w[e]);
        } else if (e < 65536) {
            int e2 = e - 32768;
            int oc = e2 >> 8, k = e2 & 255;
            C5Bs[swz(oc, k, 8)] = f2bf(c5w[e2]);
        } else {
            int e2 = e - 65536;
            int oc = e2 >> 7, k = e2 & 127;
            DWBs[swz(oc, k, 4)] = f2bf(dw[e2]);
        }
    }

    gbar(ctr, 256);

    // ================= S1: conv2 MFMA, wave-granular (672 units) ===========
    {
        int lane = tid & 63, wid = tid >> 6;
        int gw = bid * 4 + wid;           // [0, 1024)
        if (gw < 672) {                   // 672 = 4ph * 21A * 8octile
            int ph = gw / 168;
            int rem = gw % 168;
            int A = rem / 8;
            int t = rem % 8;
            int m = lane & 15, bq = lane >> 4;
            const unsigned short* wbase = W2s + (t * 6400 + lane) * 8;
            const unsigned short* pbase = P2 + ((ph * 25 + A) * 25) * 128 + 8 * bq;
            f32x4 acc0 = {0.f, 0.f, 0.f, 0.f}, acc1 = {0.f, 0.f, 0.f, 0.f};
            for (int kpos = 0; kpos < 25; ++kpos) {
                int ky = kpos / 5, kx = kpos % 5;
                const unsigned short* wp = wbase + kpos * 2048;
                const unsigned short* p0 = pbase + (ky * 25 + m + kx) * 128;
                const unsigned short* p1 = p0 + 5 * 128;
#pragma unroll
                for (int cc = 0; cc < 4; ++cc) {
                    short8 a  = *(const short8*)(wp + cc * 512);
                    short8 b0 = *(const short8*)(p0 + cc * 32);
                    short8 b1 = *(const short8*)(p1 + cc * 32);
                    acc0 = __builtin_amdgcn_mfma_f32_16x16x32_bf16(a, b0, acc0, 0, 0, 0);
                    acc1 = __builtin_amdgcn_mfma_f32_16x16x32_bf16(a, b1, acc1, 0, 0, 0);
                }
            }
            int ocb = t * 16 + 4 * bq;
            float b0v = c2b[ocb], b1v = c2b[ocb + 1], b2v = c2b[ocb + 2], b3v = c2b[ocb + 3];
            unsigned short* zrow = Z2 + ((ph * 21 + A) * 21) * 128 + ocb;
            {
                ushort4 pk;
                pk.x = f2bf(lrelu(acc0.x + b0v));
                pk.y = f2bf(lrelu(acc0.y + b1v));
                pk.z = f2bf(lrelu(acc0.z + b2v));
                pk.w = f2bf(lrelu(acc0.w + b3v));
                *(ushort4*)(zrow + m * 128) = pk;      // B = m (0..15)
            }
            if (m >= 11) {                             // B = m+5 (16..20)
                ushort4 pk;
                pk.x = f2bf(lrelu(acc1.x + b0v));
                pk.y = f2bf(lrelu(acc1.y + b1v));
                pk.z = f2bf(lrelu(acc1.z + b2v));
                pk.w = f2bf(lrelu(acc1.w + b3v));
                *(ushort4*)(zrow + (m + 5) * 128) = pk;
            }
        }
    }

    gbar(ctr, 512);

    // ================= S2: pool2 -> Q2 =====================================
    for (int t = gtid; t < 204800; t += 65536) {
        int ic = t & 127;
        int rest = t >> 7;
        int D = rest % 10;
        int C = (rest / 10) % 10;
        int qph = rest / 100;
        int iq = qph >> 2, jq = qph & 3;
        int ph1 = (iq & 1) * 2 + (jq & 1);
        int py2 = iq >> 1, px2 = jq >> 1;
        int r0 = 2 * C + py2, s0 = 2 * D + px2;
        const unsigned short* z00 = Z2 + ((ph1 * 21 + r0) * 21 + s0) * 128 + ic;
        float m0 = fmaxf(bf2f(z00[0]), bf2f(z00[128]));
        float m1 = fmaxf(bf2f(z00[21 * 128]), bf2f(z00[22 * 128]));
        Q2[t] = f2bf(fmaxf(m0, m1));
    }

    gbar(ctr, 768);

    // ================= S3: tail conv3+conv4+conv5+dense (36 blocks) ========
    if (bid < 36) {
        unsigned short* h3bf = (unsigned short*)smem;      // [16][136]
        unsigned short* h4bf = h3bf + 16 * 136;            // [16][264]
        unsigned short* h5bf = h4bf + 16 * 264;            // [16][136]
        int n0 = bid * 16;
        int lane = tid & 63, w = tid >> 6;                 // 4 waves
        int m = lane & 15, bq = lane >> 4;

        // ---- conv3: octiles {w, w+4}; B direct from Q2 ----
        {
            int p = n0 + m;
            int i = p / 24, j = p % 24;
            int qph = (i & 3) * 4 + (j & 3);
            const unsigned short* qbase = Q2 + qph * 12800 + ((i >> 2) * 10 + (j >> 2)) * 128 + 8 * bq;
            const unsigned short* wb0 = W3s + (w * 6400 + lane) * 8;
            const unsigned short* wb1 = W3s + ((w + 4) * 6400 + lane) * 8;
            f32x4 acc0 = {0.f, 0.f, 0.f, 0.f}, acc1 = {0.f, 0.f, 0.f, 0.f};
            for (int kpos = 0; kpos < 25; ++kpos) {
                int e = kpos / 5, f = kpos % 5;
                const unsigned short* qp = qbase + (e * 10 + f) * 128;
#pragma unroll
                for (int cc = 0; cc < 4; ++cc) {
                    short8 b  = *(const short8*)(qp + cc * 32);
                    short8 a0 = *(const short8*)(wb0 + kpos * 2048 + cc * 512);
                    short8 a1 = *(const short8*)(wb1 + kpos * 2048 + cc * 512);
                    acc0 = __builtin_amdgcn_mfma_f32_16x16x32_bf16(a0, b, acc0, 0, 0, 0);
                    acc1 = __builtin_amdgcn_mfma_f32_16x16x32_bf16(a1, b, acc1, 0, 0, 0);
                }
            }
            int oc0 = w * 16 + bq * 4;
            int oc1 = (w + 4) * 16 + bq * 4;
            uint2 pk0, pk1;
            pk0.x = (unsigned)f2bf(lrelu(acc0.x + c3b[oc0])) | ((unsigned)f2bf(lrelu(acc0.y + c3b[oc0 + 1])) << 16);
            pk0.y = (unsigned)f2bf(lrelu(acc0.z + c3b[oc0 + 2])) | ((unsigned)f2bf(lrelu(acc0.w + c3b[oc0 + 3])) << 16);
            pk1.x = (unsigned)f2bf(lrelu(acc1.x + c3b[oc1])) | ((unsigned)f2bf(lrelu(acc1.y + c3b[oc1 + 1])) << 16);
            pk1.y = (unsigned)f2bf(lrelu(acc1.z + c3b[oc1 + 2])) | ((unsigned)f2bf(lrelu(acc1.w + c3b[oc1 + 3])) << 16);
            *(uint2*)(&h3bf[m * 136 + oc0]) = pk0;
            *(uint2*)(&h3bf[m * 136 + oc1]) = pk1;
        }
        __syncthreads();

        // ---- conv4: octiles w*4..w*4+3, K=128 ----
        {
            f32x4 acc[4] = {{0,0,0,0},{0,0,0,0},{0,0,0,0},{0,0,0,0}};
#pragma unroll
            for (int t = 0; t < 4; ++t) {
                const unsigned short* abase = C4Bs + ((w * 4 + t) * 4 * 64 + lane) * 8;
#pragma unroll
                for (int cc = 0; cc < 4; ++cc) {
                    short8 a = *(const short8*)(abase + cc * 512);
                    short8 b = *(const short8*)(&h3bf[m * 136 + cc * 32 + 8 * bq]);
                    acc[t] = __builtin_amdgcn_mfma_f32_16x16x32_bf16(a, b, acc[t], 0, 0, 0);
                }
            }
#pragma unroll
            for (int t = 0; t < 4; ++t) {
                int oc = (w * 4 + t) * 16 + bq * 4;
                uint2 pk;
                pk.x = (unsigned)f2bf(lrelu(acc[t].x + c4b[oc])) | ((unsigned)f2bf(lrelu(acc[t].y + c4b[oc + 1])) << 16);
                pk.y = (unsigned)f2bf(lrelu(acc[t].z + c4b[oc + 2])) | ((unsigned)f2bf(lrelu(acc[t].w + c4b[oc + 3])) << 16);
                *(uint2*)(&h4bf[m * 264 + oc]) = pk;
            }
        }
        __syncthreads();

        // ---- conv5: octiles {w, w+4}, K=256 ----
        {
            f32x4 acc0 = {0.f, 0.f, 0.f, 0.f}, acc1 = {0.f, 0.f, 0.f, 0.f};
            const unsigned short* ab0 = C5Bs + (w * 8 * 64 + lane) * 8;
            const unsigned short* ab1 = C5Bs + ((w + 4) * 8 * 64 + lane) * 8;
#pragma unroll
            for (int cc = 0; cc < 8; ++cc) {
                short8 b  = *(const short8*)(&h4bf[m * 264 + cc * 32 + 8 * bq]);
                short8 a0 = *(const short8*)(ab0 + cc * 512);
                short8 a1 = *(const short8*)(ab1 + cc * 512);
                acc0 = __builtin_amdgcn_mfma_f32_16x16x32_bf16(a0, b, acc0, 0, 0, 0);
                acc1 = __builtin_amdgcn_mfma_f32_16x16x32_bf16(a1, b, acc1, 0, 0, 0);
            }
            int oc0 = w * 16 + bq * 4;
            int oc1 = (w + 4) * 16 + bq * 4;
            uint2 pk0, pk1;
            pk0.x = (unsigned)f2bf(lrelu(acc0.x + c5b[oc0])) | ((unsigned)f2bf(lrelu(acc0.y + c5b[oc0 + 1])) << 16);
            pk0.y = (unsigned)f2bf(lrelu(acc0.z + c5b[oc0 + 2])) | ((unsigned)f2bf(lrelu(acc0.w + c5b[oc0 + 3])) << 16);
            pk1.x = (unsigned)f2bf(lrelu(acc1.x + c5b[oc1])) | ((unsigned)f2bf(lrelu(acc1.y + c5b[oc1 + 1])) << 16);
            pk1.y = (unsigned)f2bf(lrelu(acc1.z + c5b[oc1 + 2])) | ((unsigned)f2bf(lrelu(acc1.w + c5b[oc1 + 3])) << 16);
            *(uint2*)(&h5bf[m * 136 + oc0]) = pk0;
            *(uint2*)(&h5bf[m * 136 + oc1]) = pk1;
        }
        __syncthreads();

        // ---- dense: octiles w*8..w*8+7, K=128 (two batches of 4) ----
#pragma unroll
        for (int batch = 0; batch < 2; ++batch) {
            f32x4 acc[4] = {{0,0,0,0},{0,0,0,0},{0,0,0,0},{0,0,0,0}};
#pragma unroll
            for (int t = 0; t < 4; ++t) {
                const unsigned short* abase = DWBs + ((w * 8 + batch * 4 + t) * 4 * 64 + lane) * 8;
#pragma unroll
                for (int cc = 0; cc < 4; ++cc) {
                    short8 a = *(const short8*)(abase + cc * 512);
                    short8 b = *(const short8*)(&h5bf[m * 136 + cc * 32 + 8 * bq]);
                    acc[t] = __builtin_amdgcn_mfma_f32_16x16x32_bf16(a, b, acc[t], 0, 0, 0);
                }
            }
#pragma unroll
            for (int t = 0; t < 4; ++t) {
                int oc = (w * 8 + batch * 4 + t) * 16 + bq * 4;
                out[(oc + 0) * 576 + n0 + m] = acc[t].x + db[oc + 0];
                out[(oc + 1) * 576 + n0 + m] = acc[t].y + db[oc + 1];
                out[(oc + 2) * 576 + n0 + m] = acc[t].z + db[oc + 2];
                out[(oc + 3) * 576 + n0 + m] = acc[t].w + db[oc + 3];
            }
        }
    }
}

extern "C" void kernel_launch(void* const* d_in, const int* in_sizes, int n_in,
                              void* d_out, int out_size, void* d_ws, size_t ws_size,
                              hipStream_t stream) {
    const float* x   = (const float*)d_in[0];
    const float* c1w = (const float*)d_in[1];
    const float* c1b = (const float*)d_in[2];
    const float* c2w = (const float*)d_in[3];
    const float* c2b = (const float*)d_in[4];
    const float* c3w = (const float*)d_in[5];
    const float* c3b = (const float*)d_in[6];
    const float* c4w = (const float*)d_in[7];
    const float* c4b = (const float*)d_in[8];
    const float* c5w = (const float*)d_in[9];
    const float* c5b = (const float*)d_in[10];
    const float* dw  = (const float*)d_in[11];
    const float* db  = (const float*)d_in[12];
    float* out = (float*)d_out;
    float* ws  = (float*)d_ws;

    unsigned* ctr = (unsigned*)(ws + 850432);
    hipMemsetAsync(ctr, 0, 64, stream);

    fused<<<256, 256, 0, stream>>>(x, c1w, c1b, c2w, c2b, c3w, c3b,
                                   c4w, c4b, c5w, c5b, dw, db, out, ws, ctr);
}

// Round 8
// 319.135 us; speedup vs baseline: 1.0611x; 1.0611x over previous
//
#include <hip/hip_runtime.h>

#define SLOPE 0.01f

typedef __attribute__((ext_vector_type(8))) short short8;
typedef __attribute__((ext_vector_type(4))) float f32x4;

__device__ __forceinline__ float lrelu(float v) { return v >= 0.f ? v : SLOPE * v; }

__device__ __forceinline__ unsigned short f2bf(float f) {
    union { float f; unsigned int u; } v; v.f = f;
    unsigned int r = v.u + 0x7fffu + ((v.u >> 16) & 1u);
    return (unsigned short)(r >> 16);
}
__device__ __forceinline__ float bf2f(unsigned short h) {
    union { unsigned int u; float f; } v; v.u = ((unsigned int)h) << 16;
    return v.f;
}

// MFMA A-fragment swizzle (16-oc tiles):
//   frag for (octile t, kblock kb) at lane l = W[((t*(K/32)+kb)*64+l)*8 .. +8)
__device__ __forceinline__ int swz(int oc, int k, int Kdiv32) {
    return (((oc >> 4) * Kdiv32 + (k >> 5)) * 64 + ((k >> 3) & 3) * 16 + (oc & 15)) * 8 + (k & 7);
}

// Two-line generation barrier. Arrivals fetch_add ctr[0]; last arriver
// (old == gen*256-1) release-stores gen to ctr[16] (separate 64B line);
// everyone else spins READ-ONLY on ctr[16] with ~0.85us s_sleep backoff.
// R7's version spun on the arrival line -> cacheline ping-pong across 8 XCDs
// -> ~100us/barrier. ctr zeroed by hipMemsetAsync each launch (graph-safe).
__device__ __forceinline__ void gbar(unsigned* __restrict__ ctr, unsigned gen) {
    __threadfence();
    __syncthreads();
    if (threadIdx.x == 0) {
        unsigned old = __hip_atomic_fetch_add(ctr, 1u, __ATOMIC_ACQ_REL, __HIP_MEMORY_SCOPE_AGENT);
        if (old == gen * 256u - 1u) {
            __hip_atomic_store(ctr + 16, gen, __ATOMIC_RELEASE, __HIP_MEMORY_SCOPE_AGENT);
        } else {
            while (__hip_atomic_load(ctr + 16, __ATOMIC_ACQUIRE, __HIP_MEMORY_SCOPE_AGENT) < gen) {
                __builtin_amdgcn_s_sleep(32);
            }
        }
    }
    __syncthreads();
    __threadfence();
}

// ---------------------------------------------------------------------------
// Workspace (f32 slot offsets):
//   P2   bf16 [4][25][25][128]   @ 0        (160000)
//   Z2   bf16 [4][21][21][128]   @ 160000   (112896)
//   W2s  bf16 swz K=3200         @ 272896   (204800)
//   W3s  bf16 swz K=3200         @ 477696   (204800)
//   C4Bs bf16 swz K=128          @ 682496   (16384)
//   C5Bs bf16 swz K=256          @ 698880   (16384)
//   DWBs bf16 swz K=128          @ 715264   (32768)
//   Q2   bf16 [16][10][10][128]  @ 748032   (102400)
//   ctr  u32[32]                 @ 850432   (arrive @ +0, release @ +64B)
// ---------------------------------------------------------------------------

__global__ __launch_bounds__(256) void fused(
    const float* __restrict__ x,
    const float* __restrict__ c1w, const float* __restrict__ c1b,
    const float* __restrict__ c2w, const float* __restrict__ c2b,
    const float* __restrict__ c3w, const float* __restrict__ c3b,
    const float* __restrict__ c4w, const float* __restrict__ c4b,
    const float* __restrict__ c5w, const float* __restrict__ c5b,
    const float* __restrict__ dw,  const float* __restrict__ db,
    float* __restrict__ out, float* __restrict__ ws, unsigned* __restrict__ ctr) {

    __shared__ float smem[9600];

    const int tid = threadIdx.x;
    const int bid = blockIdx.x;
    const int gtid = bid * 256 + tid;

    unsigned short* P2   = (unsigned short*)(ws);
    unsigned short* Z2   = (unsigned short*)(ws + 160000);
    unsigned short* W2s  = (unsigned short*)(ws + 272896);
    unsigned short* W3s  = (unsigned short*)(ws + 477696);
    unsigned short* C4Bs = (unsigned short*)(ws + 682496);
    unsigned short* C5Bs = (unsigned short*)(ws + 698880);
    unsigned short* DWBs = (unsigned short*)(ws + 715264);
    unsigned short* Q2   = (unsigned short*)(ws + 748032);

    // ================= S0a: fused conv1+pool1 -> P2 =================
    for (int idx = tid; idx < 9600; idx += 256) smem[idx] = c1w[idx];
    __syncthreads();
    for (int q = tid; q < 1250; q += 256) {
        int t = bid * 1250 + q;           // [0, 320000)
        int ic = t & 127;
        int rest = t >> 7;
        int B = rest % 25;
        int A = (rest / 25) % 25;
        int ph = rest / 625;
        int py = ph >> 1, px = ph & 1;
        int r0 = 2 * A + py, s0 = 2 * B + px;

        float a00 = 0.f, a01 = 0.f, a10 = 0.f, a11 = 0.f;
        const float* lw = smem + ic * 75;
        for (int c = 0; c < 3; ++c) {
            const float* xc = x + c * 576;
            const float* lwc = lw + c * 25;
#pragma unroll
            for (int ky = 0; ky < 5; ++ky) {
                int iy = r0 + ky - 16;
                bool v0 = (iy >= 0) && (iy < 24);
                bool v1 = (iy + 1 >= 0) && (iy + 1 < 24);
                if (!v0 && !v1) continue;
#pragma unroll
                for (int kx = 0; kx < 5; ++kx) {
                    int ix = s0 + kx - 16;
                    float w = lwc[ky * 5 + kx];
                    bool u0 = (ix >= 0) && (ix < 24);
                    bool u1 = (ix + 1 >= 0) && (ix + 1 < 24);
                    float x00 = (v0 && u0) ? xc[iy * 24 + ix] : 0.f;
                    float x01 = (v0 && u1) ? xc[iy * 24 + ix + 1] : 0.f;
                    float x10 = (v1 && u0) ? xc[(iy + 1) * 24 + ix] : 0.f;
                    float x11 = (v1 && u1) ? xc[(iy + 1) * 24 + ix + 1] : 0.f;
                    a00 += x00 * w; a01 += x01 * w; a10 += x10 * w; a11 += x11 * w;
                }
            }
        }
        float mx = fmaxf(fmaxf(a00, a01), fmaxf(a10, a11));
        P2[t] = f2bf(lrelu(c1b[ic] + mx));
    }

    // ================= S0b: W2/W3 swizzle-transpose (1 oc-row per block) ====
    {
        int oc = bid & 127;
        const float* src = (bid < 128) ? (c2w + oc * 3200) : (c3w + oc * 3200);
        unsigned short* dst = (bid < 128) ? W2s : W3s;
        __syncthreads();
        for (int idx = tid; idx < 3200; idx += 256) smem[idx] = src[idx];
        __syncthreads();
        for (int idx = tid; idx < 3200; idx += 256) {
            int ic = idx & 127, kpos = idx >> 7;
            dst[swz(oc, kpos * 128 + ic, 100)] = f2bf(smem[ic * 25 + kpos]);
        }
    }

    // ================= S0c: swizzled bf16 casts of c4w/c5w/dw ==============
    for (int q = tid; q < 512; q += 256) {
        int e = bid * 512 + q;            // [0, 131072)
        if (e < 32768) {
            int oc = e >> 7, k = e & 127;
            C4Bs[swz(oc, k, 4)] = f2bf(c4w[e]);
        } else if (e < 65536) {
            int e2 = e - 32768;
            int oc = e2 >> 8, k = e2 & 255;
            C5Bs[swz(oc, k, 8)] = f2bf(c5w[e2]);
        } else {
            int e2 = e - 65536;
            int oc = e2 >> 7, k = e2 & 127;
            DWBs[swz(oc, k, 4)] = f2bf(dw[e2]);
        }
    }

    gbar(ctr, 1);

    // ================= S1: conv2 MFMA, wave-granular (672 units) ===========
    {
        int lane = tid & 63, wid = tid >> 6;
        int gw = bid * 4 + wid;           // [0, 1024)
        if (gw < 672) {                   // 672 = 4ph * 21A * 8octile
            int ph = gw / 168;
            int rem = gw % 168;
            int A = rem / 8;
            int t = rem % 8;
            int m = lane & 15, bq = lane >> 4;
            const unsigned short* wbase = W2s + (t * 6400 + lane) * 8;
            const unsigned short* pbase = P2 + ((ph * 25 + A) * 25) * 128 + 8 * bq;
            f32x4 acc0 = {0.f, 0.f, 0.f, 0.f}, acc1 = {0.f, 0.f, 0.f, 0.f};
            for (int kpos = 0; kpos < 25; ++kpos) {
                int ky = kpos / 5, kx = kpos % 5;
                const unsigned short* wp = wbase + kpos * 2048;
                const unsigned short* p0 = pbase + (ky * 25 + m + kx) * 128;
                const unsigned short* p1 = p0 + 5 * 128;
#pragma unroll
                for (int cc = 0; cc < 4; ++cc) {
                    short8 a  = *(const short8*)(wp + cc * 512);
                    short8 b0 = *(const short8*)(p0 + cc * 32);
                    short8 b1 = *(const short8*)(p1 + cc * 32);
                    acc0 = __builtin_amdgcn_mfma_f32_16x16x32_bf16(a, b0, acc0, 0, 0, 0);
                    acc1 = __builtin_amdgcn_mfma_f32_16x16x32_bf16(a, b1, acc1, 0, 0, 0);
                }
            }
            int ocb = t * 16 + 4 * bq;
            float b0v = c2b[ocb], b1v = c2b[ocb + 1], b2v = c2b[ocb + 2], b3v = c2b[ocb + 3];
            unsigned short* zrow = Z2 + ((ph * 21 + A) * 21) * 128 + ocb;
            {
                ushort4 pk;
                pk.x = f2bf(lrelu(acc0.x + b0v));
                pk.y = f2bf(lrelu(acc0.y + b1v));
                pk.z = f2bf(lrelu(acc0.z + b2v));
                pk.w = f2bf(lrelu(acc0.w + b3v));
                *(ushort4*)(zrow + m * 128) = pk;      // B = m (0..15)
            }
            if (m >= 11) {                             // B = m+5 (16..20)
                ushort4 pk;
                pk.x = f2bf(lrelu(acc1.x + b0v));
                pk.y = f2bf(lrelu(acc1.y + b1v));
                pk.z = f2bf(lrelu(acc1.z + b2v));
                pk.w = f2bf(lrelu(acc1.w + b3v));
                *(ushort4*)(zrow + (m + 5) * 128) = pk;
            }
        }
    }

    gbar(ctr, 2);

    // ================= S2: pool2 -> Q2 =====================================
    for (int t = gtid; t < 204800; t += 65536) {
        int ic = t & 127;
        int rest = t >> 7;
        int D = rest % 10;
        int C = (rest / 10) % 10;
        int qph = rest / 100;
        int iq = qph >> 2, jq = qph & 3;
        int ph1 = (iq & 1) * 2 + (jq & 1);
        int py2 = iq >> 1, px2 = jq >> 1;
        int r0 = 2 * C + py2, s0 = 2 * D + px2;
        const unsigned short* z00 = Z2 + ((ph1 * 21 + r0) * 21 + s0) * 128 + ic;
        float m0 = fmaxf(bf2f(z00[0]), bf2f(z00[128]));
        float m1 = fmaxf(bf2f(z00[21 * 128]), bf2f(z00[22 * 128]));
        Q2[t] = f2bf(fmaxf(m0, m1));
    }

    gbar(ctr, 3);

    // ================= S3: tail conv3+conv4+conv5+dense (36 blocks) ========
    if (bid < 36) {
        unsigned short* h3bf = (unsigned short*)smem;      // [16][136]
        unsigned short* h4bf = h3bf + 16 * 136;            // [16][264]
        unsigned short* h5bf = h4bf + 16 * 264;            // [16][136]
        int n0 = bid * 16;
        int lane = tid & 63, w = tid >> 6;                 // 4 waves
        int m = lane & 15, bq = lane >> 4;

        // ---- conv3: octiles {w, w+4}; B direct from Q2 ----
        {
            int p = n0 + m;
            int i = p / 24, j = p % 24;
            int qph = (i & 3) * 4 + (j & 3);
            const unsigned short* qbase = Q2 + qph * 12800 + ((i >> 2) * 10 + (j >> 2)) * 128 + 8 * bq;
            const unsigned short* wb0 = W3s + (w * 6400 + lane) * 8;
            const unsigned short* wb1 = W3s + ((w + 4) * 6400 + lane) * 8;
            f32x4 acc0 = {0.f, 0.f, 0.f, 0.f}, acc1 = {0.f, 0.f, 0.f, 0.f};
            for (int kpos = 0; kpos < 25; ++kpos) {
                int e = kpos / 5, f = kpos % 5;
                const unsigned short* qp = qbase + (e * 10 + f) * 128;
#pragma unroll
                for (int cc = 0; cc < 4; ++cc) {
                    short8 b  = *(const short8*)(qp + cc * 32);
                    short8 a0 = *(const short8*)(wb0 + kpos * 2048 + cc * 512);
                    short8 a1 = *(const short8*)(wb1 + kpos * 2048 + cc * 512);
                    acc0 = __builtin_amdgcn_mfma_f32_16x16x32_bf16(a0, b, acc0, 0, 0, 0);
                    acc1 = __builtin_amdgcn_mfma_f32_16x16x32_bf16(a1, b, acc1, 0, 0, 0);
                }
            }
            int oc0 = w * 16 + bq * 4;
            int oc1 = (w + 4) * 16 + bq * 4;
            uint2 pk0, pk1;
            pk0.x = (unsigned)f2bf(lrelu(acc0.x + c3b[oc0])) | ((unsigned)f2bf(lrelu(acc0.y + c3b[oc0 + 1])) << 16);
            pk0.y = (unsigned)f2bf(lrelu(acc0.z + c3b[oc0 + 2])) | ((unsigned)f2bf(lrelu(acc0.w + c3b[oc0 + 3])) << 16);
            pk1.x = (unsigned)f2bf(lrelu(acc1.x + c3b[oc1])) | ((unsigned)f2bf(lrelu(acc1.y + c3b[oc1 + 1])) << 16);
            pk1.y = (unsigned)f2bf(lrelu(acc1.z + c3b[oc1 + 2])) | ((unsigned)f2bf(lrelu(acc1.w + c3b[oc1 + 3])) << 16);
            *(uint2*)(&h3bf[m * 136 + oc0]) = pk0;
            *(uint2*)(&h3bf[m * 136 + oc1]) = pk1;
        }
        __syncthreads();

        // ---- conv4: octiles w*4..w*4+3, K=128 ----
        {
            f32x4 acc[4] = {{0,0,0,0},{0,0,0,0},{0,0,0,0},{0,0,0,0}};
#pragma unroll
            for (int t = 0; t < 4; ++t) {
                const unsigned short* abase = C4Bs + ((w * 4 + t) * 4 * 64 + lane) * 8;
#pragma unroll
                for (int cc = 0; cc < 4; ++cc) {
                    short8 a = *(const short8*)(abase + cc * 512);
                    short8 b = *(const short8*)(&h3bf[m * 136 + cc * 32 + 8 * bq]);
                    acc[t] = __builtin_amdgcn_mfma_f32_16x16x32_bf16(a, b, acc[t], 0, 0, 0);
                }
            }
#pragma unroll
            for (int t = 0; t < 4; ++t) {
                int oc = (w * 4 + t) * 16 + bq * 4;
                uint2 pk;
                pk.x = (unsigned)f2bf(lrelu(acc[t].x + c4b[oc])) | ((unsigned)f2bf(lrelu(acc[t].y + c4b[oc + 1])) << 16);
                pk.y = (unsigned)f2bf(lrelu(acc[t].z + c4b[oc + 2])) | ((unsigned)f2bf(lrelu(acc[t].w + c4b[oc + 3])) << 16);
                *(uint2*)(&h4bf[m * 264 + oc]) = pk;
            }
        }
        __syncthreads();

        // ---- conv5: octiles {w, w+4}, K=256 ----
        {
            f32x4 acc0 = {0.f, 0.f, 0.f, 0.f}, acc1 = {0.f, 0.f, 0.f, 0.f};
            const unsigned short* ab0 = C5Bs + (w * 8 * 64 + lane) * 8;
            const unsigned short* ab1 = C5Bs + ((w + 4) * 8 * 64 + lane) * 8;
#pragma unroll
            for (int cc = 0; cc < 8; ++cc) {
                short8 b  = *(const short8*)(&h4bf[m * 264 + cc * 32 + 8 * bq]);
                short8 a0 = *(const short8*)(ab0 + cc * 512);
                short8 a1 = *(const short8*)(ab1 + cc * 512);
                acc0 = __builtin_amdgcn_mfma_f32_16x16x32_bf16(a0, b, acc0, 0, 0, 0);
                acc1 = __builtin_amdgcn_mfma_f32_16x16x32_bf16(a1, b, acc1, 0, 0, 0);
            }
            int oc0 = w * 16 + bq * 4;
            int oc1 = (w + 4) * 16 + bq * 4;
            uint2 pk0, pk1;
            pk0.x = (unsigned)f2bf(lrelu(acc0.x + c5b[oc0])) | ((unsigned)f2bf(lrelu(acc0.y + c5b[oc0 + 1])) << 16);
            pk0.y = (unsigned)f2bf(lrelu(acc0.z + c5b[oc0 + 2])) | ((unsigned)f2bf(lrelu(acc0.w + c5b[oc0 + 3])) << 16);
            pk1.x = (unsigned)f2bf(lrelu(acc1.x + c5b[oc1])) | ((unsigned)f2bf(lrelu(acc1.y + c5b[oc1 + 1])) << 16);
            pk1.y = (unsigned)f2bf(lrelu(acc1.z + c5b[oc1 + 2])) | ((unsigned)f2bf(lrelu(acc1.w + c5b[oc1 + 3])) << 16);
            *(uint2*)(&h5bf[m * 136 + oc0]) = pk0;
            *(uint2*)(&h5bf[m * 136 + oc1]) = pk1;
        }
        __syncthreads();

        // ---- dense: octiles w*8..w*8+7, K=128 (two batches of 4) ----
#pragma unroll
        for (int batch = 0; batch < 2; ++batch) {
            f32x4 acc[4] = {{0,0,0,0},{0,0,0,0},{0,0,0,0},{0,0,0,0}};
#pragma unroll
            for (int t = 0; t < 4; ++t) {
                const unsigned short* abase = DWBs + ((w * 8 + batch * 4 + t) * 4 * 64 + lane) * 8;
#pragma unroll
                for (int cc = 0; cc < 4; ++cc) {
                    short8 a = *(const short8*)(abase + cc * 512);
                    short8 b = *(const short8*)(&h5bf[m * 136 + cc * 32 + 8 * bq]);
                    acc[t] = __builtin_amdgcn_mfma_f32_16x16x32_bf16(a, b, acc[t], 0, 0, 0);
                }
            }
#pragma unroll
            for (int t = 0; t < 4; ++t) {
                int oc = (w * 8 + batch * 4 + t) * 16 + bq * 4;
                out[(oc + 0) * 576 + n0 + m] = acc[t].x + db[oc + 0];
                out[(oc + 1) * 576 + n0 + m] = acc[t].y + db[oc + 1];
                out[(oc + 2) * 576 + n0 + m] = acc[t].z + db[oc + 2];
                out[(oc + 3) * 576 + n0 + m] = acc[t].w + db[oc + 3];
            }
        }
    }
}

extern "C" void kernel_launch(void* const* d_in, const int* in_sizes, int n_in,
                              void* d_out, int out_size, void* d_ws, size_t ws_size,
                              hipStream_t stream) {
    const float* x   = (const float*)d_in[0];
    const float* c1w = (const float*)d_in[1];
    const float* c1b = (const float*)d_in[2];
    const float* c2w = (const float*)d_in[3];
    const float* c2b = (const float*)d_in[4];
    const float* c3w = (const float*)d_in[5];
    const float* c3b = (const float*)d_in[6];
    const float* c4w = (const float*)d_in[7];
    const float* c4b = (const float*)d_in[8];
    const float* c5w = (const float*)d_in[9];
    const float* c5b = (const float*)d_in[10];
    const float* dw  = (const float*)d_in[11];
    const float* db  = (const float*)d_in[12];
    float* out = (float*)d_out;
    float* ws  = (float*)d_ws;

    unsigned* ctr = (unsigned*)(ws + 850432);
    hipMemsetAsync(ctr, 0, 128, stream);

    fused<<<256, 256, 0, stream>>>(x, c1w, c1b, c2w, c2b, c3w, c3b,
                                   c4w, c4b, c5w, c5b, dw, db, out, ws, ctr);
}